// Round 5
// baseline (229.627 us; speedup 1.0000x reference)
//
#include <hip/hip_runtime.h>
#include <hip/hip_bf16.h>

#define DEV __device__ __forceinline__

typedef __attribute__((ext_vector_type(8))) short short8;
typedef __attribute__((ext_vector_type(4))) float f32x4;
typedef __attribute__((ext_vector_type(16))) float f32x16;
typedef __attribute__((ext_vector_type(2))) unsigned int u32x2;
typedef __attribute__((ext_vector_type(4))) unsigned int u32x4;
typedef unsigned short u16;
typedef unsigned int u32;

// B=4, T=2048, D=1024, H=16, E=64, M = B*T = 8192

DEV u16 f2bf(float f) {
    union { __hip_bfloat16 h; u16 u; } cv;
    cv.h = __float2bfloat16(f);
    return cv.u;
}

// raw HW exp2 (1 TRANS op; args here are <= ~1.45)
DEV float exp2_raw(float x) {
    float r;
    asm("v_exp_f32 %0, %1" : "=v"(r) : "v"(x));
    return r;
}

// packed f32x2 -> bf16x2, RNE (1 VALU op); src0 -> low half
DEV u32 cvtpk_bf2(float lo, float hi) {
    u32 r;
    asm("v_cvt_pk_bf16_f32 %0, %1, %2" : "=v"(r) : "v"(lo), "v"(hi));
    return r;
}

DEV float max3f(float a, float b, float c) { return fmaxf(fmaxf(a, b), c); }

DEV void gload_lds16(const void* g, void* l) {
    __builtin_amdgcn_global_load_lds((const __attribute__((address_space(1))) u32*)g,
                                     (__attribute__((address_space(3))) u32*)l, 16, 0, 0);
}

// ---------- transpose fp32 -> bf16 : 3-way merged for Wq/Wk/Wv ----------
__global__ __launch_bounds__(256) void k_transpose_w3(const float* __restrict__ W0,
                                                      const float* __restrict__ W1,
                                                      const float* __restrict__ W2,
                                                      u16* __restrict__ O0,
                                                      u16* __restrict__ O1,
                                                      u16* __restrict__ O2) {
    __shared__ float tile[64][65];
    const int x = threadIdx.x & 63, y = threadIdx.x >> 6;
    const int which = blockIdx.z >> 4, slab_i = blockIdx.z & 15;
    const float* in = which == 0 ? W0 : (which == 1 ? W1 : W2);
    u16* out = which == 0 ? O0 : (which == 1 ? O1 : O2);
    const long slab = (long)slab_i * 1024 * 64;
    const int r0 = blockIdx.x * 64;
#pragma unroll
    for (int i = 0; i < 16; ++i) {
        int rr = y + 4 * i;
        tile[rr][x] = in[slab + (long)(r0 + rr) * 64 + x];
    }
    __syncthreads();
#pragma unroll
    for (int i = 0; i < 16; ++i) {
        int cc = y + 4 * i;
        out[slab + (long)cc * 1024 + (r0 + x)] = f2bf(tile[x][cc]);
    }
}

__global__ __launch_bounds__(256) void k_transpose_f32_bf16(const float* __restrict__ in,
                                                            u16* __restrict__ out,
                                                            int R, int C) {
    __shared__ float tile[64][65];
    const int x = threadIdx.x & 63, y = threadIdx.x >> 6;
    const long slab = (long)blockIdx.z * R * C;
    const int r0 = blockIdx.x * 64, c0 = blockIdx.y * 64;
#pragma unroll
    for (int i = 0; i < 16; ++i) {
        int rr = y + 4 * i;
        tile[rr][x] = in[slab + (long)(r0 + rr) * C + (c0 + x)];
    }
    __syncthreads();
#pragma unroll
    for (int i = 0; i < 16; ++i) {
        int cc = y + 4 * i;
        out[slab + (long)(c0 + cc) * R + (r0 + x)] = f2bf(tile[x][cc]);
    }
}

// ---------- transpose bf16 -> bf16 ----------
__global__ __launch_bounds__(256) void k_transpose_bf16(const u16* __restrict__ in,
                                                        u16* __restrict__ out,
                                                        int R, int C) {
    __shared__ u16 tile[64][65];
    const int x = threadIdx.x & 63, y = threadIdx.x >> 6;
    const long slab = (long)blockIdx.z * R * C;
    const int r0 = blockIdx.x * 64, c0 = blockIdx.y * 64;
#pragma unroll
    for (int i = 0; i < 16; ++i) {
        int rr = y + 4 * i;
        tile[rr][x] = in[slab + (long)(r0 + rr) * C + (c0 + x)];
    }
    __syncthreads();
#pragma unroll
    for (int i = 0; i < 16; ++i) {
        int cc = y + 4 * i;
        out[slab + (long)(c0 + cc) * R + (r0 + x)] = tile[x][cc];
    }
}

// ---------- GEMMs: M=8192, N=1024, K=1024, BM=BN=128, BK=32 ----------
// LDS tiles [128][32] bf16, 16B chunks; slot swizzle: s = q ^ ((row>>1)&3)
// (row stride 64B = half bank rotation; using row bit1 spreads 16 rows over
//  8 bank-groups -> 2-way = free). Double-buffered, ONE barrier per K-step.

// merged Q/K/V projection: A fp32 (reg-staged, T14 async-split), B via gload_lds
__global__ __launch_bounds__(256) void k_gemm3(const float* __restrict__ A0, const float* __restrict__ A1,
                                               const float* __restrict__ A2,
                                               const u16* __restrict__ B0, const u16* __restrict__ B1,
                                               const u16* __restrict__ B2,
                                               u16* __restrict__ C0, u16* __restrict__ C1,
                                               u16* __restrict__ C2) {
    __shared__ u16 As[2][4096];
    __shared__ u16 Bs[2][4096];
    const int z = blockIdx.z;
    const float* Af = z == 0 ? A0 : (z == 1 ? A1 : A2);
    const u16*   Bt = z == 0 ? B0 : (z == 1 ? B1 : B2);
    u16*         Cb = z == 0 ? C0 : (z == 1 ? C1 : C2);

    const int tid = threadIdx.x;
    const int lane = tid & 63, wave = tid >> 6;
    const int l15 = lane & 15, l4 = lane >> 4;
    const int wr = wave >> 1, wc = wave & 1;
    const int brow = blockIdx.x * 128, bcol = blockIdx.y * 128;

    // staging geometry: chunks c0=tid, c1=tid+256; r=c>>2, q=c&3
    const int rA0 = tid >> 2,        qA0 = tid & 3,        sA0 = qA0 ^ ((rA0 >> 1) & 3);
    const int rA1 = (tid + 256) >> 2, qA1 = tid & 3,       sA1 = qA1 ^ ((rA1 >> 1) & 3);
    const float* arow0 = Af + (long)(brow + rA0) * 1024 + qA0 * 8;
    const float* arow1 = Af + (long)(brow + rA1) * 1024 + qA1 * 8;
    const u16* brow0 = Bt + (long)(bcol + rA0) * 1024 + sA0 * 8;
    const u16* brow1 = Bt + (long)(bcol + rA1) * 1024 + sA1 * 8;

    // hoisted frag offsets (elem index), rows 16-aligned per m/n
    int offA[4], offB[4];
#pragma unroll
    for (int m = 0; m < 4; ++m) {
        const int ra = wr * 64 + m * 16 + l15;
        offA[m] = ra * 32 + (l4 ^ ((ra >> 1) & 3)) * 8;
        const int rb = wc * 64 + m * 16 + l15;
        offB[m] = rb * 32 + (l4 ^ ((rb >> 1) & 3)) * 8;
    }

    f32x4 acc[4][4] = {};
    float4 va0, va1, vb0, vb1;

    // prologue: tile 0
    va0 = ((const float4*)arow0)[0]; va1 = ((const float4*)(arow0 + 4))[0];
    vb0 = ((const float4*)arow1)[0]; vb1 = ((const float4*)(arow1 + 4))[0];
    gload_lds16(brow0, &Bs[0][wave * 512]);
    gload_lds16(brow1, &Bs[0][2048 + wave * 512]);
    {
        u32x4 w;
        w[0] = cvtpk_bf2(va0.x, va0.y); w[1] = cvtpk_bf2(va0.z, va0.w);
        w[2] = cvtpk_bf2(va1.x, va1.y); w[3] = cvtpk_bf2(va1.z, va1.w);
        *(u32x4*)&As[0][rA0 * 32 + sA0 * 8] = w;
        w[0] = cvtpk_bf2(vb0.x, vb0.y); w[1] = cvtpk_bf2(vb0.z, vb0.w);
        w[2] = cvtpk_bf2(vb1.x, vb1.y); w[3] = cvtpk_bf2(vb1.z, vb1.w);
        *(u32x4*)&As[0][rA1 * 32 + sA1 * 8] = w;
    }

#pragma unroll 2
    for (int t = 0; t < 32; ++t) {
        const int buf = t & 1;
        __syncthreads();                   // tile t staged (vm+lgkm drained); WAR-safe
        const int k1 = (t + 1) * 32;
        if (t < 31) {                      // issue next-tile loads (latency hides under MFMA)
            va0 = ((const float4*)(arow0 + k1))[0]; va1 = ((const float4*)(arow0 + k1 + 4))[0];
            vb0 = ((const float4*)(arow1 + k1))[0]; vb1 = ((const float4*)(arow1 + k1 + 4))[0];
            gload_lds16(brow0 + k1, &Bs[buf ^ 1][wave * 512]);
            gload_lds16(brow1 + k1, &Bs[buf ^ 1][2048 + wave * 512]);
        }

        short8 af[4], bfr[4];
#pragma unroll
        for (int m = 0; m < 4; ++m) af[m] = *(const short8*)&As[buf][offA[m]];
#pragma unroll
        for (int n = 0; n < 4; ++n) bfr[n] = *(const short8*)&Bs[buf][offB[n]];
#pragma unroll
        for (int m = 0; m < 4; ++m)
#pragma unroll
            for (int n = 0; n < 4; ++n)
                acc[m][n] = __builtin_amdgcn_mfma_f32_16x16x32_bf16(af[m], bfr[n], acc[m][n], 0, 0, 0);

        if (t < 31) {                      // convert + write A for t+1 (after MFMA issue)
            u32x4 w;
            w[0] = cvtpk_bf2(va0.x, va0.y); w[1] = cvtpk_bf2(va0.z, va0.w);
            w[2] = cvtpk_bf2(va1.x, va1.y); w[3] = cvtpk_bf2(va1.z, va1.w);
            *(u32x4*)&As[buf ^ 1][rA0 * 32 + sA0 * 8] = w;
            w[0] = cvtpk_bf2(vb0.x, vb0.y); w[1] = cvtpk_bf2(vb0.z, vb0.w);
            w[2] = cvtpk_bf2(vb1.x, vb1.y); w[3] = cvtpk_bf2(vb1.z, vb1.w);
            *(u32x4*)&As[buf ^ 1][rA1 * 32 + sA1 * 8] = w;
        }
    }

    // epilogue: D lane layout: row=(lane>>4)*4+r, col=lane&15 ; C -> bf16 [b][h][t][e]
#pragma unroll
    for (int m = 0; m < 4; ++m)
#pragma unroll
        for (int n = 0; n < 4; ++n)
#pragma unroll
            for (int r = 0; r < 4; ++r) {
                const int g = brow + wr * 64 + m * 16 + l4 * 4 + r;
                const int ng = bcol + wc * 64 + n * 16 + l15;
                const int b = g >> 11, tt = g & 2047;
                const int h = ng >> 6, e = ng & 63;
                Cb[(long)(b * 16 + h) * 131072 + (long)tt * 64 + e] = f2bf(acc[m][n][r]);
            }
}

// output projection: A = bf16 attn [b][h][t][e] gathered (gload_lds); C fp32
__global__ __launch_bounds__(256) void k_gemm_out(const u16* __restrict__ Ab,
                                                  const u16* __restrict__ Bt,
                                                  float* __restrict__ Cf) {
    __shared__ u16 As[2][4096];
    __shared__ u16 Bs[2][4096];
    const int tid = threadIdx.x;
    const int lane = tid & 63, wave = tid >> 6;
    const int l15 = lane & 15, l4 = lane >> 4;
    const int wr = wave >> 1, wc = wave & 1;
    const int brow = blockIdx.x * 128, bcol = blockIdx.y * 128;

    const int rA0 = tid >> 2,         qA0 = tid & 3, sA0 = qA0 ^ ((rA0 >> 1) & 3);
    const int rA1 = (tid + 256) >> 2, sA1 = qA0 ^ ((rA1 >> 1) & 3);
    const int g0 = brow + rA0, b0 = g0 >> 11, t0 = g0 & 2047;
    const int g1 = brow + rA1, b1 = g1 >> 11, t1 = g1 & 2047;
    const u16* a0 = Ab + (long)(b0 * 16) * 131072 + (long)t0 * 64 + sA0 * 8;
    const u16* a1 = Ab + (long)(b1 * 16) * 131072 + (long)t1 * 64 + sA1 * 8;
    const u16* brow0 = Bt + (long)(bcol + rA0) * 1024 + sA0 * 8;
    const u16* brow1 = Bt + (long)(bcol + rA1) * 1024 + sA1 * 8;

    int offA[4], offB[4];
#pragma unroll
    for (int m = 0; m < 4; ++m) {
        const int ra = wr * 64 + m * 16 + l15;
        offA[m] = ra * 32 + (l4 ^ ((ra >> 1) & 3)) * 8;
        const int rb = wc * 64 + m * 16 + l15;
        offB[m] = rb * 32 + (l4 ^ ((rb >> 1) & 3)) * 8;
    }

    f32x4 acc[4][4] = {};

#define STAGE_O(buf, t) do {                                                      \
    const int k0_ = (t) * 32;                                                     \
    const int h_ = k0_ >> 6;    /* head */                                        \
    const long hs_ = (long)h_ * 131072 + (k0_ & 63);                              \
    gload_lds16(a0 + hs_, &As[buf][wave * 512]);                                  \
    gload_lds16(a1 + hs_, &As[buf][2048 + wave * 512]);                           \
    gload_lds16(brow0 + k0_, &Bs[buf][wave * 512]);                               \
    gload_lds16(brow1 + k0_, &Bs[buf][2048 + wave * 512]);                        \
  } while (0)

    STAGE_O(0, 0);

#pragma unroll 2
    for (int t = 0; t < 32; ++t) {
        const int buf = t & 1;
        __syncthreads();
        if (t < 31) STAGE_O(buf ^ 1, t + 1);

        short8 af[4], bfr[4];
#pragma unroll
        for (int m = 0; m < 4; ++m) af[m] = *(const short8*)&As[buf][offA[m]];
#pragma unroll
        for (int n = 0; n < 4; ++n) bfr[n] = *(const short8*)&Bs[buf][offB[n]];
#pragma unroll
        for (int m = 0; m < 4; ++m)
#pragma unroll
            for (int n = 0; n < 4; ++n)
                acc[m][n] = __builtin_amdgcn_mfma_f32_16x16x32_bf16(af[m], bfr[n], acc[m][n], 0, 0, 0);
    }
#undef STAGE_O

#pragma unroll
    for (int m = 0; m < 4; ++m)
#pragma unroll
        for (int n = 0; n < 4; ++n)
#pragma unroll
            for (int r = 0; r < 4; ++r) {
                const int g = brow + wr * 64 + m * 16 + l4 * 4 + r;
                const int ng = bcol + wc * 64 + n * 16 + l15;
                Cf[(long)g * 1024 + ng] = acc[m][n][r];
            }
}

// ---------- flash attention v4: 32x32 MFMA, in-register softmax, lean VALU ----------
__global__ __launch_bounds__(256, 4) void k_flash4(const u16* __restrict__ Qh,
                                                   const u16* __restrict__ Kh,
                                                   const u16* __restrict__ VhT,
                                                   u16* __restrict__ attn) {
    __shared__ u16 Ks[2][4096];   // [kv][d], 16B chunks XOR-swizzled by row&7
    __shared__ u16 Vs[2][4096];   // [e][kv], same swizzle

    const int tid = threadIdx.x, lane = tid & 63, w = tid >> 6;
    const int l31 = lane & 31, l5 = lane >> 5;
    const int wid = blockIdx.x;
    const int swz = (wid & 7) * 128 + (wid >> 3);   // bijective: 1024 % 8 == 0
    const int bh = swz >> 4, qt = swz & 15;
    const long base = (long)bh * (2048 * 64);
    const int q = qt * 128 + w * 32 + l31;          // this lane's q row

    short8 qf[4];
    {
        const u16* qp = Qh + base + (long)q * 64 + l5 * 8;
#pragma unroll
        for (int ksd = 0; ksd < 4; ++ksd) qf[ksd] = *(const short8*)(qp + ksd * 16);
    }

    int off[4];
#pragma unroll
    for (int ksd = 0; ksd < 4; ++ksd)
        off[ksd] = l31 * 128 + (((ksd * 2 + l5) ^ (l31 & 7)) << 4);

    const float CEXP = 0.18033688011112042f;   // 0.125 * log2(e)
    float mr = -INFINITY;
    f32x16 oacc0 = {}, oacc1 = {}, lacc = {};

    short8 ones;
#pragma unroll
    for (int j = 0; j < 8; ++j) ones[j] = (short)0x3F80;

    const int c0 = tid, c1 = tid + 256;
    const int r0 = c0 >> 3, s0 = (c0 & 7) ^ (r0 & 7);
    const int r1 = c1 >> 3, s1 = (c1 & 7) ^ (r1 & 7);

#define STAGE(buf, t) do {                                                              \
    const long kv0_ = (long)((t) * 64);                                                 \
    gload_lds16(Kh + base + (kv0_ + r0) * 64 + s0 * 8, &Ks[buf][w * 512]);              \
    gload_lds16(Kh + base + (kv0_ + r1) * 64 + s1 * 8, &Ks[buf][2048 + w * 512]);       \
    gload_lds16(VhT + base + (long)r0 * 2048 + kv0_ + s0 * 8, &Vs[buf][w * 512]);       \
    gload_lds16(VhT + base + (long)r1 * 2048 + kv0_ + s1 * 8, &Vs[buf][2048 + w * 512]); \
  } while (0)

    STAGE(0, 0);

#pragma unroll 2
    for (int t = 0; t < 32; ++t) {
        const int buf = t & 1;
        __syncthreads();
        if (t < 31) STAGE(buf ^ 1, t + 1);

        const char* Kb = (const char*)&Ks[buf][0];
        const char* Vb = (const char*)&Vs[buf][0];

        f32x16 z0 = {}, z1 = {};
#pragma unroll
        for (int ksd = 0; ksd < 4; ++ksd) {
            short8 kf0 = *(const short8*)(Kb + off[ksd]);
            z0 = __builtin_amdgcn_mfma_f32_32x32x16_bf16(kf0, qf[ksd], z0, 0, 0, 0);
            short8 kf1 = *(const short8*)(Kb + 4096 + off[ksd]);
            z1 = __builtin_amdgcn_mfma_f32_32x32x16_bf16(kf1, qf[ksd], z1, 0, 0, 0);
        }

        float a0 = max3f(z0[0],  z0[1],  z0[2]);
        float a1 = max3f(z0[3],  z0[4],  z0[5]);
        float a2 = max3f(z0[6],  z0[7],  z0[8]);
        float a3 = max3f(z0[9],  z0[10], z0[11]);
        float a4 = max3f(z0[12], z0[13], z0[14]);
        float a5 = max3f(z0[15], z1[0],  z1[1]);
        float a6 = max3f(z1[2],  z1[3],  z1[4]);
        float a7 = max3f(z1[5],  z1[6],  z1[7]);
        float a8 = max3f(z1[8],  z1[9],  z1[10]);
        float a9 = max3f(z1[11], z1[12], z1[13]);
        float aa = fmaxf(z1[14], z1[15]);
        float b0 = max3f(a0, a1, a2);
        float b1 = max3f(a3, a4, a5);
        float b2 = max3f(a6, a7, a8);
        float b3 = fmaxf(a9, aa);
        float vm = fmaxf(max3f(b0, b1, b2), b3);
        {
            u32x2 pp = __builtin_amdgcn_permlane32_swap(__builtin_bit_cast(u32, vm),
                                                        __builtin_bit_cast(u32, vm), false, false);
            vm = fmaxf(__builtin_bit_cast(float, pp[0]), __builtin_bit_cast(float, pp[1]));
        }
        if (!__all(vm - mr <= 8.0f)) {     // T13 defer-max (raw THR=8 -> P <= e)
            const float nm = fmaxf(mr, vm);
            const float sc = exp2_raw((mr - nm) * CEXP);
            mr = nm;
#pragma unroll
            for (int i = 0; i < 16; ++i) { oacc0[i] *= sc; oacc1[i] *= sc; }
            lacc[0] *= sc;
        }
        const float nmc = -mr * CEXP;

#pragma unroll
        for (int tile = 0; tile < 2; ++tile) {
            const f32x16& zz = tile ? z1 : z0;
            u32 W[8];
#pragma unroll
            for (int mw = 0; mw < 8; ++mw) {
                const float p0 = exp2_raw(fmaf(zz[2 * mw],     CEXP, nmc));
                const float p1 = exp2_raw(fmaf(zz[2 * mw + 1], CEXP, nmc));
                W[mw] = cvtpk_bf2(p0, p1);
            }
#pragma unroll
            for (int ksw = 0; ksw < 2; ++ksw) {
                const int ks = tile * 2 + ksw;
                u32x2 ra = __builtin_amdgcn_permlane32_swap(W[4 * ksw + 0], W[4 * ksw + 2], false, false);
                u32x2 rb = __builtin_amdgcn_permlane32_swap(W[4 * ksw + 1], W[4 * ksw + 3], false, false);
                u32x4 pw; pw[0] = ra[0]; pw[1] = rb[0]; pw[2] = ra[1]; pw[3] = rb[1];
                const short8 pb = __builtin_bit_cast(short8, pw);
                short8 vf0 = *(const short8*)(Vb + off[ks]);
                oacc0 = __builtin_amdgcn_mfma_f32_32x32x16_bf16(vf0, pb, oacc0, 0, 0, 0);
                short8 vf1 = *(const short8*)(Vb + 4096 + off[ks]);
                oacc1 = __builtin_amdgcn_mfma_f32_32x32x16_bf16(vf1, pb, oacc1, 0, 0, 0);
                lacc = __builtin_amdgcn_mfma_f32_32x32x16_bf16(ones, pb, lacc, 0, 0, 0);
            }
        }
    }
#undef STAGE

    const float inv = 1.0f / lacc[0];
    u16* op = attn + base + (long)q * 64;
#pragma unroll
    for (int et = 0; et < 2; ++et) {
        const f32x16& oa = et ? oacc1 : oacc0;
#pragma unroll
        for (int rq = 0; rq < 4; ++rq) {
            u32x2 st;
            st[0] = cvtpk_bf2(oa[4 * rq + 0] * inv, oa[4 * rq + 1] * inv);
            st[1] = cvtpk_bf2(oa[4 * rq + 2] * inv, oa[4 * rq + 3] * inv);
            *(u32x2*)(op + et * 32 + rq * 8 + l5 * 4) = st;
        }
    }
}

extern "C" void kernel_launch(void* const* d_in, const int* in_sizes, int n_in,
                              void* d_out, int out_size, void* d_ws, size_t ws_size,
                              hipStream_t stream) {
    (void)in_sizes; (void)n_in; (void)out_size; (void)ws_size;
    const float* Q  = (const float*)d_in[0];
    const float* K  = (const float*)d_in[1];
    const float* V  = (const float*)d_in[2];
    const float* Wq = (const float*)d_in[3];
    const float* Wk = (const float*)d_in[4];
    const float* Wv = (const float*)d_in[5];
    const float* Wo = (const float*)d_in[6];

    char* ws = (char*)d_ws;
    auto WS = [&](size_t mb) { return (u16*)(ws + (mb << 20)); };
    u16* WqT  = WS(0);    // [1024][1024] bf16 (B^T layouts)   2MB each
    u16* WkT  = WS(2);
    u16* WvT  = WS(4);
    u16* WoT  = WS(6);
    u16* Qh   = WS(8);    // [64][2048][64] bf16   16MB each
    u16* Kh   = WS(24);
    u16* Vh   = WS(40);
    u16* VhT  = WS(56);   // [64][64][2048]
    u16* attn = WS(72);   // [64][2048][64]        ends at 88MB

    dim3 b256(256);
    // weights -> B^T bf16. Wq/Wk/Wv merged: per head [1024d][64e] -> [64e][1024d]
    k_transpose_w3<<<dim3(16, 1, 48), b256, 0, stream>>>(Wq, Wk, Wv, WqT, WkT, WvT);
    // Wo: [1024 he][1024 D] -> [1024 D][1024 he]
    k_transpose_f32_bf16<<<dim3(16, 16, 1), b256, 0, stream>>>(Wo, WoT, 1024, 1024);

    // merged Q/K/V projections
    k_gemm3<<<dim3(64, 8, 3), b256, 0, stream>>>(Q, K, V, WqT, WkT, WvT, Qh, Kh, Vh);

    // V transpose per (b,h): [2048][64] -> [64][2048]
    k_transpose_bf16<<<dim3(32, 1, 64), b256, 0, stream>>>(Vh, VhT, 2048, 64);

    // attention
    k_flash4<<<dim3(1024), b256, 0, stream>>>(Qh, Kh, VhT, attn);

    // output projection
    k_gemm_out<<<dim3(64, 8), b256, 0, stream>>>(attn, WoT, (float*)d_out);
}